// Round 4
// baseline (607.425 us; speedup 1.0000x reference)
//
#include <hip/hip_runtime.h>
#include <math.h>

#define BB   64
#define CC   1024
#define HWC  144
#define KK   8192
#define MM   9216
#define NBN  32          // number of 256-code bn blocks

typedef __attribute__((ext_vector_type(8))) short          bf16x8;
typedef __attribute__((ext_vector_type(8))) unsigned short u16x8;
typedef __attribute__((ext_vector_type(4))) float          f32x4;

// ws byte layout
#define FA_BYTES  ((size_t)MM * CC * 2 * 2)   // hi+lo bf16
#define FB_BYTES  ((size_t)KK * CC * 2 * 2)
#define OFF_FA    0
#define OFF_FB    (OFF_FA + FA_BYTES)
#define OFF_ESQ   (OFF_FB + FB_BYTES)
#define OFF_PM    (OFF_ESQ + (size_t)KK * 4)
#define OFF_PS    (OFF_PM + (size_t)NBN * MM * 4)
#define OFF_FACT  (OFF_PS + (size_t)NBN * MM * 4)

__device__ inline unsigned short f2bf(float x) {
    union { float f; unsigned u; } v; v.f = x;
    unsigned r = v.u + 0x7fffu + ((v.u >> 16) & 1u);
    return (unsigned short)(r >> 16);
}
__device__ inline float bf2f(unsigned short h) {
    union { unsigned u; float f; } v; v.u = (unsigned)h << 16;
    return v.f;
}

// ---------------------------------------------------------------------------
// Prep A: crop + transpose + bf16 hi/lo split into 256-row k-major tiles.
// Tile (bm,kt) = 32 KB: [which(2)][chunk(4)][row(256)] x 16B (8 bf16 of
// A[row][kt*32 + chunk*8 + e]).
__global__ __launch_bounds__(256)
void prep_A(const float* __restrict__ feat, u16x8* __restrict__ fA) {
    __shared__ float tile[64][145];
    int cb = blockIdx.x;      // 16 channel blocks of 64
    int b  = blockIdx.y;
    for (int idx = threadIdx.x; idx < 64 * 144; idx += 256) {
        int r = idx / 144, hw = idx - r * 144;
        int h = hw / 12, w = hw - h * 12;
        tile[r][hw] = feat[(size_t)((b * 1024 + cb * 64 + r) * 196)
                           + (h + 1) * 14 + (w + 1)];
    }
    __syncthreads();
    for (int idx = threadIdx.x; idx < 8 * 144; idx += 256) {
        int g = idx / 144, hw = idx - g * 144;       // hw fastest -> coalesced
        int p = b * 144 + hw;
        int bm = p >> 8, row = p & 255;
        int cg = cb * 64 + g * 8;
        int kt = cg >> 5, chunk = (cg >> 3) & 3;
        u16x8 hi, lo;
#pragma unroll
        for (int e = 0; e < 8; ++e) {
            float x = tile[g * 8 + e][hw];
            unsigned short h16 = f2bf(x);
            hi[e] = (short)h16;
            lo[e] = (short)f2bf(x - bf2f(h16));
        }
        size_t base = (size_t)(bm * 32 + kt) * 2048 + chunk * 256 + row;
        fA[base] = hi;
        fA[base + 1024] = lo;
    }
}

// Prep B: same tiling for embedding (256-col tiles).
__global__ __launch_bounds__(256)
void prep_B(const float* __restrict__ emb, u16x8* __restrict__ fB) {
    __shared__ float tile[128][65];
    int cb = blockIdx.x;      // 16 channel blocks of 64
    int nb = blockIdx.y;      // 64 n blocks of 128
#pragma unroll
    for (int i = 0; i < 8; ++i) {
        int idx = threadIdx.x + i * 256;             // < 2048
        int nl = idx >> 4, c4 = idx & 15;
        const float4 v = *reinterpret_cast<const float4*>(
            emb + (size_t)(nb * 128 + nl) * 1024 + cb * 64 + c4 * 4);
        tile[nl][c4 * 4 + 0] = v.x;
        tile[nl][c4 * 4 + 1] = v.y;
        tile[nl][c4 * 4 + 2] = v.z;
        tile[nl][c4 * 4 + 3] = v.w;
    }
    __syncthreads();
#pragma unroll
    for (int i = 0; i < 4; ++i) {
        int idx = threadIdx.x + i * 256;             // < 1024
        int kc = idx >> 7, rl = idx & 127;           // rl fastest -> coalesced
        int ktl = kc >> 2, chunk = kc & 3;
        int cl = ktl * 32 + chunk * 8;
        int n = nb * 128 + rl;
        int bn = n >> 8, row = n & 255;
        u16x8 hi, lo;
#pragma unroll
        for (int e = 0; e < 8; ++e) {
            float x = tile[rl][cl + e];
            unsigned short h16 = f2bf(x);
            hi[e] = (short)h16;
            lo[e] = (short)f2bf(x - bf2f(h16));
        }
        int kt = cb * 2 + ktl;
        size_t base = (size_t)(bn * 32 + kt) * 2048 + chunk * 256 + row;
        fB[base] = hi;
        fB[base + 1024] = lo;
    }
}

// Row sum-of-squares for embedding (fp32 exact)
__global__ void rowsumsq(const float* __restrict__ src, float* __restrict__ dst) {
    int row = blockIdx.x * 4 + (threadIdx.x >> 6);
    int l = threadIdx.x & 63;
    const float4* p = reinterpret_cast<const float4*>(src + (size_t)row * 1024);
    float s = 0.f;
#pragma unroll
    for (int it = 0; it < 4; ++it) {
        float4 v = p[l + it * 64];
        s += v.x * v.x + v.y * v.y + v.z * v.z + v.w * v.w;
    }
#pragma unroll
    for (int off = 32; off; off >>= 1) s += __shfl_down(s, off);
    if (l == 0) dst[row] = s;
}

// ---------------------------------------------------------------------------
// 256x256 MFMA GEMM (bf16x3 split) + fused partial softmax epilogue.
// 8 waves (2 wr x 4 wc), BK=32, 2x64KB LDS buffers, counted vmcnt pipeline.
__global__ __launch_bounds__(512, 1)
void gemm_mfma(const char* __restrict__ fA, const char* __restrict__ fB,
               const float* __restrict__ esq, const float* __restrict__ mdm,
               float* __restrict__ codes, float* __restrict__ pm,
               float* __restrict__ ps) {
    __shared__ __align__(16) char smem[131072];

    int flat = blockIdx.x;                    // 1152 = 8 * 144
    int swz = (flat & 7) * 144 + (flat >> 3); // XCD-aware, bijective
    int bm = swz >> 5, bn = swz & 31;

    int tid = threadIdx.x;
    int l = tid & 63, lr = l & 15, lc = l >> 4;
    int wv = tid >> 6, wr = wv >> 2, wc = wv & 3;

    const char* gA = fA + (size_t)bm * 1048576;
    const char* gB = fB + (size_t)bn * 1048576;

    f32x4 acc[8][4];
#pragma unroll
    for (int i = 0; i < 8; ++i)
#pragma unroll
        for (int j = 0; j < 4; ++j) acc[i][j] = (f32x4){0.f, 0.f, 0.f, 0.f};

    auto stage = [&](int buf, int kt) {
        char* db = smem + buf * 65536;
        const char* ga = gA + (size_t)kt * 32768;
        const char* gb = gB + (size_t)kt * 32768;
#pragma unroll
        for (int i = 0; i < 4; ++i) {
            int off = i * 8192 + tid * 16;
            __builtin_amdgcn_global_load_lds(
                (const __attribute__((address_space(1))) void*)(ga + off),
                (__attribute__((address_space(3))) void*)(db + off), 16, 0, 0);
            __builtin_amdgcn_global_load_lds(
                (const __attribute__((address_space(1))) void*)(gb + off),
                (__attribute__((address_space(3))) void*)(db + 32768 + off), 16, 0, 0);
        }
    };

    stage(0, 0);
    stage(1, 1);                 // 16 loads/wave outstanding

    for (int kt = 0; kt < 32; ++kt) {
        // tile kt ready when only tile kt+1's 8 loads remain outstanding
        asm volatile("s_waitcnt vmcnt(8)" ::: "memory");
        __builtin_amdgcn_s_barrier();
        __builtin_amdgcn_sched_barrier(0);

        const char* bufc = smem + (kt & 1) * 65536;
        bf16x8 bh[4], bl[4];
#pragma unroll
        for (int fj = 0; fj < 4; ++fj) {
            int bo = 32768 + lc * 4096 + (wc * 64 + fj * 16 + lr) * 16;
            bh[fj] = *(const bf16x8*)(bufc + bo);
            bl[fj] = *(const bf16x8*)(bufc + 16384 + bo);
        }
#pragma unroll
        for (int half = 0; half < 2; ++half) {
            bf16x8 ah[4], al[4];
#pragma unroll
            for (int f = 0; f < 4; ++f) {
                int ao = lc * 4096 + (wr * 128 + (half * 4 + f) * 16 + lr) * 16;
                ah[f] = *(const bf16x8*)(bufc + ao);
                al[f] = *(const bf16x8*)(bufc + 16384 + ao);
            }
            __builtin_amdgcn_s_setprio(1);
#pragma unroll
            for (int f = 0; f < 4; ++f)
#pragma unroll
                for (int fj = 0; fj < 4; ++fj) {
                    f32x4& A = acc[half * 4 + f][fj];
                    A = __builtin_amdgcn_mfma_f32_16x16x32_bf16(ah[f], bh[fj], A, 0, 0, 0);
                    A = __builtin_amdgcn_mfma_f32_16x16x32_bf16(ah[f], bl[fj], A, 0, 0, 0);
                    A = __builtin_amdgcn_mfma_f32_16x16x32_bf16(al[f], bh[fj], A, 0, 0, 0);
                }
            __builtin_amdgcn_s_setprio(0);
        }
        __builtin_amdgcn_s_barrier();        // all waves done reading buf
        int kn = (kt + 2 > 31) ? 31 : kt + 2; // clamp keeps vmcnt counts uniform
        stage(kt & 1, kn);
    }

    asm volatile("s_waitcnt vmcnt(0)" ::: "memory");
    __builtin_amdgcn_s_barrier();

    // ---- fused partial-softmax epilogue (base-2 domain) ----
    float invl2 = (15.0f / mdm[0]) * 1.44269504089f;
    float s2 = 2.0f * invl2;
    float e2[4];
#pragma unroll
    for (int fj = 0; fj < 4; ++fj)
        e2[fj] = invl2 * esq[bn * 256 + wc * 64 + fj * 16 + lr];

#pragma unroll
    for (int fi = 0; fi < 8; ++fi)
#pragma unroll
        for (int fj = 0; fj < 4; ++fj)
#pragma unroll
            for (int j = 0; j < 4; ++j)
                acc[fi][fj][j] = s2 * acc[fi][fj][j] - e2[fj];

    float mx[8][4];
#pragma unroll
    for (int fi = 0; fi < 8; ++fi)
#pragma unroll
        for (int j = 0; j < 4; ++j) {
            float m = fmaxf(fmaxf(acc[fi][0][j], acc[fi][1][j]),
                            fmaxf(acc[fi][2][j], acc[fi][3][j]));
            mx[fi][j] = m;
        }
#pragma unroll
    for (int off = 1; off < 16; off <<= 1)
#pragma unroll
        for (int fi = 0; fi < 8; ++fi)
#pragma unroll
            for (int j = 0; j < 4; ++j)
                mx[fi][j] = fmaxf(mx[fi][j], __shfl_xor(mx[fi][j], off));

    float* maxb = (float*)smem;            // [4][256]
    float* sumb = (float*)smem + 1024;     // [4][256]
    if (lr == 0) {
#pragma unroll
        for (int fi = 0; fi < 8; ++fi)
#pragma unroll
            for (int j = 0; j < 4; ++j)
                maxb[wc * 256 + wr * 128 + fi * 16 + lc * 4 + j] = mx[fi][j];
    }
    __syncthreads();

    float mp[8][4];
#pragma unroll
    for (int fi = 0; fi < 8; ++fi)
#pragma unroll
        for (int j = 0; j < 4; ++j) {
            int row = wr * 128 + fi * 16 + lc * 4 + j;
            mp[fi][j] = fmaxf(fmaxf(maxb[row], maxb[256 + row]),
                              fmaxf(maxb[512 + row], maxb[768 + row]));
        }

    float ss[8][4];
#pragma unroll
    for (int fi = 0; fi < 8; ++fi)
#pragma unroll
        for (int j = 0; j < 4; ++j) ss[fi][j] = 0.f;
#pragma unroll
    for (int fi = 0; fi < 8; ++fi)
#pragma unroll
        for (int fj = 0; fj < 4; ++fj)
#pragma unroll
            for (int j = 0; j < 4; ++j) {
                float E = exp2f(acc[fi][fj][j] - mp[fi][j]);
                acc[fi][fj][j] = E;
                ss[fi][j] += E;
            }
#pragma unroll
    for (int off = 1; off < 16; off <<= 1)
#pragma unroll
        for (int fi = 0; fi < 8; ++fi)
#pragma unroll
            for (int j = 0; j < 4; ++j)
                ss[fi][j] += __shfl_xor(ss[fi][j], off);
    if (lr == 0) {
#pragma unroll
        for (int fi = 0; fi < 8; ++fi)
#pragma unroll
            for (int j = 0; j < 4; ++j)
                sumb[wc * 256 + wr * 128 + fi * 16 + lc * 4 + j] = ss[fi][j];
    }
    __syncthreads();
    if (tid < 256) {
        int p = bm * 256 + tid;
        pm[(size_t)bn * MM + p] = fmaxf(fmaxf(maxb[tid], maxb[256 + tid]),
                                        fmaxf(maxb[512 + tid], maxb[768 + tid]));
        ps[(size_t)bn * MM + p] = sumb[tid] + sumb[256 + tid]
                                + sumb[512 + tid] + sumb[768 + tid];
    }

    // NT-store E
#pragma unroll
    for (int fi = 0; fi < 8; ++fi) {
        int p0 = bm * 256 + wr * 128 + fi * 16 + lc * 4;
        int b = p0 / 144, hw = p0 - b * 144;
#pragma unroll
        for (int fj = 0; fj < 4; ++fj) {
            int k = bn * 256 + wc * 64 + fj * 16 + lr;
            __builtin_nontemporal_store(
                acc[fi][fj],
                (f32x4*)(codes + ((size_t)(b * 8192 + k)) * 144 + hw));
        }
    }
}

// ---------------------------------------------------------------------------
// Combine partials: factor[bn][p] = 2^(pm - m_glob) / S
__global__ void comb_factor(const float* __restrict__ pm,
                            const float* __restrict__ ps,
                            float* __restrict__ factor) {
    int p = blockIdx.x * 256 + threadIdx.x;      // 9216 = 36*256
    float m = -INFINITY;
#pragma unroll 8
    for (int bn = 0; bn < NBN; ++bn) m = fmaxf(m, pm[(size_t)bn * MM + p]);
    float S = 0.f;
#pragma unroll 8
    for (int bn = 0; bn < NBN; ++bn)
        S += ps[(size_t)bn * MM + p] * exp2f(pm[(size_t)bn * MM + p] - m);
    float is = 1.f / S;
#pragma unroll 8
    for (int bn = 0; bn < NBN; ++bn)
        factor[(size_t)bn * MM + p] = exp2f(pm[(size_t)bn * MM + p] - m) * is;
}

// ---------------------------------------------------------------------------
// codes = E * factor (in place), bow[r] = max over hw. One wave per row.
__global__ __launch_bounds__(256)
void scale_bow(float* __restrict__ codes, const float* __restrict__ factor,
               float* __restrict__ bow) {
    int wid = threadIdx.x >> 6, l = threadIdx.x & 63;
    int r = blockIdx.x * 4 + wid;                // b*8192 + k
    int b = r >> 13, k = r & 8191;
    f32x4* Cp = (f32x4*)(codes + (size_t)r * 144);
    const f32x4* Fp = (const f32x4*)(factor + (size_t)(k >> 8) * MM + b * 144);
    float m = 0.f;
    if (l < 36) {
        f32x4 e = __builtin_nontemporal_load(Cp + l);
        f32x4 f = Fp[l];
        f32x4 v = e * f;
        __builtin_nontemporal_store(v, Cp + l);
        m = fmaxf(fmaxf(v.x, v.y), fmaxf(v.z, v.w));
    }
#pragma unroll
    for (int off = 32; off; off >>= 1) m = fmaxf(m, __shfl_down(m, off));
    if (l == 0) bow[r] = m;
}

// L1-normalize bow per b
__global__ void bow_norm(float* __restrict__ bow) {
    __shared__ float lds[4];
    __shared__ float stot;
    int b = blockIdx.x;
    float* p = bow + b * 8192;
    float s = 0.f;
    for (int i = threadIdx.x; i < 8192; i += 256) s += fabsf(p[i]);
#pragma unroll
    for (int off = 32; off; off >>= 1) s += __shfl_down(s, off);
    int wid = threadIdx.x >> 6, l = threadIdx.x & 63;
    if (l == 0) lds[wid] = s;
    __syncthreads();
    if (threadIdx.x == 0) stot = 1.f / (lds[0] + lds[1] + lds[2] + lds[3]);
    __syncthreads();
    float inv = stot;
    for (int i = threadIdx.x; i < 8192; i += 256) p[i] *= inv;
}

// ---------------------------------------------------------------------------
extern "C" void kernel_launch(void* const* d_in, const int* in_sizes, int n_in,
                              void* d_out, int out_size, void* d_ws, size_t ws_size,
                              hipStream_t stream) {
    const float* feat = (const float*)d_in[0];
    const float* emb  = (const float*)d_in[1];
    const float* mdm  = (const float*)d_in[2];
    float* bow   = (float*)d_out;
    float* codes = (float*)d_out + (size_t)BB * KK;

    char* ws = (char*)d_ws;
    u16x8* fA    = (u16x8*)(ws + OFF_FA);
    u16x8* fB    = (u16x8*)(ws + OFF_FB);
    float* esq   = (float*)(ws + OFF_ESQ);
    float* pm    = (float*)(ws + OFF_PM);
    float* ps    = (float*)(ws + OFF_PS);
    float* fact  = (float*)(ws + OFF_FACT);

    prep_A<<<dim3(16, 64), 256, 0, stream>>>(feat, fA);
    prep_B<<<dim3(16, 64), 256, 0, stream>>>(emb, fB);
    rowsumsq<<<KK / 4, 256, 0, stream>>>(emb, esq);
    gemm_mfma<<<1152, 512, 0, stream>>>((const char*)fA, (const char*)fB,
                                        esq, mdm, codes, pm, ps);
    comb_factor<<<36, 256, 0, stream>>>(pm, ps, fact);
    scale_bow<<<(BB * KK) / 4, 256, 0, stream>>>(codes, fact, bow);
    bow_norm<<<BB, 256, 0, stream>>>(bow);
}